// Round 2
// baseline (4305.367 us; speedup 1.0000x reference)
//
#include <hip/hip_runtime.h>
#include <math.h>

#define B_ 4
#define T_ 8192
#define D_ 1024
#define H_ 8
#define HD_ 128
#define C_ 64
#define N_ 128
#define BT_ (B_*T_)
#define BH_ (B_*H_)

typedef unsigned short ushort_t;
typedef unsigned long long ull_t;

__device__ __forceinline__ void fma4(float4& a, float s, const float4& v) {
  a.x += s*v.x; a.y += s*v.y; a.z += s*v.z; a.w += s*v.w;
}
__device__ __forceinline__ float bfu(unsigned int u16) {   // low 16 bits = bf16
  return __uint_as_float(u16 << 16);
}
__device__ __forceinline__ ushort_t f2bf(float f) {
  unsigned int x = __float_as_uint(f);
  x += 0x7FFFu + ((x >> 16) & 1u);
  return (ushort_t)(x >> 16);
}
__device__ __forceinline__ ull_t pack4bf(float a, float b, float c, float d) {
  return (ull_t)f2bf(a) | ((ull_t)f2bf(b) << 16) | ((ull_t)f2bf(c) << 32) | ((ull_t)f2bf(d) << 48);
}

// ---------------------------------------------------------------------------
// Kernel 1: per-token projections -> gate, beta, decay(raw), innorm.
// grid = B*T blocks, 256 threads.
// ---------------------------------------------------------------------------
__global__ __launch_bounds__(256) void k1_proj(
    const float* __restrict__ x, const float* __restrict__ Wg,
    const float* __restrict__ Wb, const float* __restrict__ Wa,
    const float* __restrict__ dt_bias, const float* __restrict__ A_log,
    float* __restrict__ gate_buf, float* __restrict__ beta_buf,
    float* __restrict__ decay_buf, float* __restrict__ innorm_buf) {
  const int row = blockIdx.x;
  const int b = row / T_, t = row % T_;
  const int tid = threadIdx.x;
  __shared__ float xs[D_];
  __shared__ float red[3][H_][4];
  __shared__ float scal[3][H_];
  __shared__ float rnorm[H_];

  ((float4*)xs)[tid] = ((const float4*)(x + (size_t)row * D_))[tid];
  __syncthreads();

  float pg[H_], pb[H_], pa[H_];
  #pragma unroll
  for (int h = 0; h < H_; h++) { pg[h] = 0.f; pb[h] = 0.f; pa[h] = 0.f; }
  for (int i = tid; i < D_; i += 256) {
    float xv = xs[i];
    #pragma unroll
    for (int h = 0; h < H_; h++) {
      pg[h] += xv * Wg[h*D_ + i];
      pb[h] += xv * Wb[h*D_ + i];
      pa[h] += xv * Wa[h*D_ + i];
    }
  }
  const int lane = tid & 63, wv = tid >> 6;
  #pragma unroll
  for (int h = 0; h < H_; h++) {
    float g = pg[h], bb = pb[h], aa = pa[h];
    #pragma unroll
    for (int off = 32; off > 0; off >>= 1) {
      g  += __shfl_down(g, off);
      bb += __shfl_down(bb, off);
      aa += __shfl_down(aa, off);
    }
    if (lane == 0) { red[0][h][wv] = g; red[1][h][wv] = bb; red[2][h][wv] = aa; }
  }
  // per-head sum of squares (32 threads per head, 4 elems each)
  float pn;
  {
    int hh = tid >> 5, e0 = (tid & 31) * 4;
    const float* xh = xs + hh*HD_ + e0;
    pn = xh[0]*xh[0] + xh[1]*xh[1] + xh[2]*xh[2] + xh[3]*xh[3];
  }
  #pragma unroll
  for (int off = 16; off > 0; off >>= 1) pn += __shfl_down(pn, off, 32);
  __syncthreads();
  if ((tid & 31) == 0) rnorm[tid >> 5] = fmaxf(sqrtf(pn), 1e-12f);
  if (tid < 24) {
    int p = tid >> 3, h = tid & 7;
    scal[p][h] = red[p][h][0] + red[p][h][1] + red[p][h][2] + red[p][h][3];
  }
  __syncthreads();
  if (tid < H_) {
    int h = tid;
    float g  = 1.f / (1.f + expf(-scal[0][h]));
    float be = 1.f / (1.f + expf(-scal[1][h]));
    float z  = scal[2][h] + dt_bias[h];
    float sp = (z > 20.f) ? z : log1pf(expf(z));
    float dc = -expf(A_log[h]) * sp;
    size_t idx = (size_t)(b*H_ + h)*T_ + t;
    gate_buf[idx] = g; beta_buf[idx] = be; decay_buf[idx] = dc;
    innorm_buf[idx] = 1.f / rnorm[h];
  }
}

// ---------------------------------------------------------------------------
// GEMM: C[M,N] = A[M,K] @ W[N,K]^T (+ R).  128x128 tile, BK=8, 256 threads.
// ---------------------------------------------------------------------------
__global__ __launch_bounds__(256) void k_gemm(
    const float* __restrict__ A, const float* __restrict__ W,
    const float* __restrict__ R, float* __restrict__ C,
    int M, int N, int K) {
  __shared__ float As[8][132];
  __shared__ float Ws[8][132];
  const int tid = threadIdx.x;
  const int tx = tid & 15, ty = tid >> 4;
  const int row0 = blockIdx.y * 128, col0 = blockIdx.x * 128;
  const int lr = tid >> 1, lk = (tid & 1) * 4;
  float acc[8][8];
  #pragma unroll
  for (int i = 0; i < 8; i++)
    #pragma unroll
    for (int j = 0; j < 8; j++) acc[i][j] = 0.f;
  const float* Ap = A + (size_t)(row0 + lr)*K + lk;
  const float* Wp = W + (size_t)(col0 + lr)*K + lk;
  for (int k0 = 0; k0 < K; k0 += 8) {
    float4 av = *(const float4*)(Ap + k0);
    float4 wv = *(const float4*)(Wp + k0);
    As[lk+0][lr] = av.x; As[lk+1][lr] = av.y; As[lk+2][lr] = av.z; As[lk+3][lr] = av.w;
    Ws[lk+0][lr] = wv.x; Ws[lk+1][lr] = wv.y; Ws[lk+2][lr] = wv.z; Ws[lk+3][lr] = wv.w;
    __syncthreads();
    #pragma unroll
    for (int k = 0; k < 8; k++) {
      float4 a0 = *(const float4*)&As[k][ty*4];
      float4 a1 = *(const float4*)&As[k][64 + ty*4];
      float4 b0 = *(const float4*)&Ws[k][tx*4];
      float4 b1 = *(const float4*)&Ws[k][64 + tx*4];
      float aa[8] = {a0.x,a0.y,a0.z,a0.w,a1.x,a1.y,a1.z,a1.w};
      float bb[8] = {b0.x,b0.y,b0.z,b0.w,b1.x,b1.y,b1.z,b1.w};
      #pragma unroll
      for (int i = 0; i < 8; i++)
        #pragma unroll
        for (int j = 0; j < 8; j++) acc[i][j] += aa[i]*bb[j];
    }
    __syncthreads();
  }
  #pragma unroll
  for (int i = 0; i < 8; i++) {
    int r = row0 + ((i < 4) ? (ty*4 + i) : (64 + ty*4 + i - 4));
    #pragma unroll
    for (int jh = 0; jh < 2; jh++) {
      int c = col0 + jh*64 + tx*4;
      float4 v;
      v.x = acc[i][jh*4+0]; v.y = acc[i][jh*4+1]; v.z = acc[i][jh*4+2]; v.w = acc[i][jh*4+3];
      if (R) {
        float4 rr = *(const float4*)&R[(size_t)r*N + c];
        v.x += rr.x; v.y += rr.y; v.z += rr.z; v.w += rr.w;
      }
      *(float4*)&C[(size_t)r*N + c] = v;
    }
  }
}

// ---------------------------------------------------------------------------
// Kernel 3: per-chunk UT transform.  grid = BH*N, 256 threads.  LDS ~52 KB.
// Pool holds keys (65x132) then aliases v-tile (64x128).
// U packs M (strict lower: U[i][j], j<i) and A^T (upper: U[j][i], i>=j).
// Transforms v -> A@(v*beta) IN PLACE in v_io; writes wkcd (bf16), attn (bf16), dec.
// ---------------------------------------------------------------------------
__global__ __launch_bounds__(256) void k3_chunk(
    const float* __restrict__ x, float* __restrict__ v_io,
    const float* __restrict__ beta_buf, const float* __restrict__ decay_buf,
    const float* __restrict__ innorm_buf,
    ushort_t* __restrict__ wkcd_buf, ushort_t* __restrict__ attn_buf,
    float* __restrict__ dec_buf) {
  const int blk = blockIdx.x;
  const int bh = blk >> 7, n = blk & 127;
  const int b = bh >> 3, h = bh & 7;
  const int t0 = n * C_;
  const int tid = threadIdx.x;
  __shared__ float Pool[65*132];
  __shared__ float U[C_][66];
  __shared__ float dec[C_], beta_s[C_], edec[C_], inn[65];

  if (tid < 65) {
    int tg = t0 - 1 + tid;
    inn[tid] = (tg >= 0) ? innorm_buf[(size_t)bh*T_ + tg] : 0.f;
  }
  if (tid >= 192) {
    int i = tid - 192;
    size_t g = (size_t)bh*T_ + t0 + i;
    beta_s[i] = beta_buf[g];
    dec[i] = decay_buf[g];
  }
  __syncthreads();
  for (int idx = tid; idx < 65*32; idx += 256) {
    int i = idx >> 5, e4 = (idx & 31) * 4;
    int tg = t0 - 1 + i;
    float4 v = {0.f,0.f,0.f,0.f};
    if (tg >= 0) {
      v = *(const float4*)&x[((size_t)b*T_ + tg)*D_ + h*HD_ + e4];
      float s = inn[i];
      v.x*=s; v.y*=s; v.z*=s; v.w*=s;
    }
    *(float4*)&Pool[i*132 + e4] = v;
  }
  __syncthreads();
  if (tid == 0) { float s = 0.f; for (int i = 0; i < C_; i++) { s += dec[i]; dec[i] = s; } }
  __syncthreads();
  if (tid < C_) {
    edec[tid] = expf(dec[tid]);
    dec_buf[(size_t)bh*T_ + t0 + tid] = dec[tid];
  }
  // --- M (strict lower of U) and attn ---
  const int bi = tid >> 4, bj = tid & 15;
  const int i0m = bi*4, j0m = bj*4;
  if (bi >= bj) {
    float m[4][4] = {{0.f}}, am[4][4] = {{0.f}};
    for (int k = 0; k < HD_; k += 4) {
      float4 wb[4];
      #pragma unroll
      for (int c = 0; c < 4; c++) wb[c] = *(const float4*)&Pool[(j0m+c)*132 + k];
      #pragma unroll
      for (int r = 0; r < 4; r++) {
        float4 wa = *(const float4*)&Pool[(i0m+r)*132 + k];
        float4 ra = *(const float4*)&Pool[(i0m+1+r)*132 + k];
        #pragma unroll
        for (int c = 0; c < 4; c++) {
          m[r][c]  += wa.x*wb[c].x + wa.y*wb[c].y + wa.z*wb[c].z + wa.w*wb[c].w;
          am[r][c] += ra.x*wb[c].x + ra.y*wb[c].y + ra.z*wb[c].z + ra.w*wb[c].w;
        }
      }
    }
    #pragma unroll
    for (int r = 0; r < 4; r++) {
      int i = i0m + r;
      #pragma unroll
      for (int c = 0; c < 4; c++) {
        int j = j0m + c;
        if (j < i) U[i][j] = m[r][c] * beta_s[i] * expf(dec[i]-dec[j]);
      }
      float a0 = (j0m+0 <= i) ? am[r][0]*expf(dec[i]-dec[j0m+0]) : 0.f;
      float a1 = (j0m+1 <= i) ? am[r][1]*expf(dec[i]-dec[j0m+1]) : 0.f;
      float a2 = (j0m+2 <= i) ? am[r][2]*expf(dec[i]-dec[j0m+2]) : 0.f;
      float a3 = (j0m+3 <= i) ? am[r][3]*expf(dec[i]-dec[j0m+3]) : 0.f;
      *(ull_t*)&attn_buf[(((size_t)bh*N_ + n)*C_ + i)*C_ + j0m] = pack4bf(a0,a1,a2,a3);
    }
  } else {
    #pragma unroll
    for (int r = 0; r < 4; r++) {
      int i = i0m + r;
      *(ull_t*)&attn_buf[(((size_t)bh*N_ + n)*C_ + i)*C_ + j0m] = 0ull;
    }
  }
  __syncthreads();
  // --- forward substitution: thread j owns column j of A (upper of U) ---
  if (tid < C_) {
    int j = tid;
    U[j][j] = 1.f;
    for (int i = j + 1; i < C_; i++) {
      float s = 0.f;
      for (int l = j; l < i; l++) s += U[i][l] * U[j][l];
      U[j][i] = -s;
    }
  }
  __syncthreads();
  // --- scale wk rows by beta*e^dec ---
  for (int idx = tid; idx < C_*32; idx += 256) {
    int i = idx >> 5, e4 = (idx & 31) * 4;
    float s = beta_s[i] * edec[i];
    float4 v = *(const float4*)&Pool[i*132 + e4];
    v.x*=s; v.y*=s; v.z*=s; v.w*=s;
    *(float4*)&Pool[i*132 + e4] = v;
  }
  __syncthreads();
  // --- wkcd = A @ (wk*beta*e^dec) -> bf16 global ---
  const int i0 = (tid >> 4) * 4, e0 = (tid & 15) * 8;
  {
    float acc[4][8];
    #pragma unroll
    for (int r = 0; r < 4; r++)
      #pragma unroll
      for (int c = 0; c < 8; c++) acc[r][c] = 0.f;
    for (int j = 0; j < i0; j++) {
      float a0=U[j][i0], a1=U[j][i0+1], a2=U[j][i0+2], a3=U[j][i0+3];
      float4 w0 = *(const float4*)&Pool[j*132 + e0];
      float4 w1 = *(const float4*)&Pool[j*132 + e0 + 4];
      float ww[8] = {w0.x,w0.y,w0.z,w0.w,w1.x,w1.y,w1.z,w1.w};
      float aa[4] = {a0,a1,a2,a3};
      #pragma unroll
      for (int r = 0; r < 4; r++)
        #pragma unroll
        for (int c = 0; c < 8; c++) acc[r][c] += aa[r]*ww[c];
    }
    #pragma unroll
    for (int jj = 0; jj < 4; jj++) {
      int j = i0 + jj;
      float4 w0 = *(const float4*)&Pool[j*132 + e0];
      float4 w1 = *(const float4*)&Pool[j*132 + e0 + 4];
      float ww[8] = {w0.x,w0.y,w0.z,w0.w,w1.x,w1.y,w1.z,w1.w};
      for (int r = jj; r < 4; r++) {
        float a = U[j][i0+r];
        #pragma unroll
        for (int c = 0; c < 8; c++) acc[r][c] += a*ww[c];
      }
    }
    #pragma unroll
    for (int r = 0; r < 4; r++) {
      size_t base = ((size_t)bh*T_ + t0 + i0 + r)*HD_ + e0;
      *(ull_t*)&wkcd_buf[base]   = pack4bf(acc[r][0],acc[r][1],acc[r][2],acc[r][3]);
      *(ull_t*)&wkcd_buf[base+4] = pack4bf(acc[r][4],acc[r][5],acc[r][6],acc[r][7]);
    }
  }
  __syncthreads();
  // --- load v tile (beta-scaled) OVER Pool (stride 128) ---
  for (int idx = tid; idx < C_*32; idx += 256) {
    int i = idx >> 5, e4 = (idx & 31) * 4;
    float4 v = *(const float4*)&v_io[((size_t)b*T_ + t0 + i)*D_ + h*HD_ + e4];
    float s = beta_s[i];
    v.x*=s; v.y*=s; v.z*=s; v.w*=s;
    *(float4*)&Pool[i*128 + e4] = v;
  }
  __syncthreads();
  // --- v' = A @ (v*beta) -> write back in place (fp32) ---
  {
    float acc[4][8];
    #pragma unroll
    for (int r = 0; r < 4; r++)
      #pragma unroll
      for (int c = 0; c < 8; c++) acc[r][c] = 0.f;
    for (int j = 0; j < i0; j++) {
      float aa[4] = {U[j][i0], U[j][i0+1], U[j][i0+2], U[j][i0+3]};
      float4 v0 = *(const float4*)&Pool[j*128 + e0];
      float4 v1 = *(const float4*)&Pool[j*128 + e0 + 4];
      float vv[8] = {v0.x,v0.y,v0.z,v0.w,v1.x,v1.y,v1.z,v1.w};
      #pragma unroll
      for (int r = 0; r < 4; r++)
        #pragma unroll
        for (int c = 0; c < 8; c++) acc[r][c] += aa[r]*vv[c];
    }
    #pragma unroll
    for (int jj = 0; jj < 4; jj++) {
      int j = i0 + jj;
      float4 v0 = *(const float4*)&Pool[j*128 + e0];
      float4 v1 = *(const float4*)&Pool[j*128 + e0 + 4];
      float vv[8] = {v0.x,v0.y,v0.z,v0.w,v1.x,v1.y,v1.z,v1.w};
      for (int r = jj; r < 4; r++) {
        float a = U[j][i0+r];
        #pragma unroll
        for (int c = 0; c < 8; c++) acc[r][c] += a*vv[c];
      }
    }
    #pragma unroll
    for (int r = 0; r < 4; r++) {
      size_t base = ((size_t)b*T_ + t0 + i0 + r)*D_ + h*HD_ + e0;
      float4 v0 = {acc[r][0],acc[r][1],acc[r][2],acc[r][3]};
      float4 v1 = {acc[r][4],acc[r][5],acc[r][6],acc[r][7]};
      *(float4*)&v_io[base]     = v0;
      *(float4*)&v_io[base + 4] = v1;
    }
  }
}

// ---------------------------------------------------------------------------
// Kernel 4: inter-chunk scan.  grid = BH*8 (16-col slices), 256 thr. LDS ~59 KB.
// PoolF: phase1 = wkcd bf16 (aliased), phase2/3 = keys fp32 (65x132).
// Writes gated o IN PLACE over v' in v_io.
// ---------------------------------------------------------------------------
__global__ __launch_bounds__(256) void k4_scan(
    const float* __restrict__ x, float* __restrict__ v_io,
    const ushort_t* __restrict__ wkcd_buf, const ushort_t* __restrict__ attn_buf,
    const float* __restrict__ dec_buf, const float* __restrict__ gate_buf,
    const float* __restrict__ innorm_buf) {
  const int bh = blockIdx.x >> 3;
  const int e0b = (blockIdx.x & 7) * 16;
  const int b = bh >> 3, h = bh & 7;
  const int tid = threadIdx.x;
  __shared__ float S[HD_][20];
  __shared__ float PoolF[65*132];
  __shared__ ushort_t attn_s[C_][66];
  __shared__ float Vn[C_][20];
  __shared__ float dec_s[C_], edec[C_], dw[C_], gate_s[C_], inn[65];
  ushort_t* wkcd_s = (ushort_t*)PoolF;

  for (int idx = tid; idx < HD_*20; idx += 256) (&S[0][0])[idx] = 0.f;

  const int ib = tid >> 2, cb4 = (tid & 3) * 4;   // v_new & o phases: row ib, 4 cols
  const int kr = tid >> 1, cb8 = (tid & 1) * 8;   // S-update: row kr, 8 cols

  for (int n = 0; n < N_; n++) {
    const int t0 = n * C_;
    __syncthreads();
    // phase-0 loads: wkcd (bf16), attn (bf16), smalls, innorm
    for (int idx = tid; idx < C_*64; idx += 256) {
      int i = idx >> 6, e2 = idx & 63;
      ((unsigned int*)&wkcd_s[i*132])[e2] =
          ((const unsigned int*)&wkcd_buf[((size_t)bh*T_ + t0 + i)*HD_])[e2];
    }
    for (int idx = tid; idx < C_*32; idx += 256) {
      int i = idx >> 5, e2 = idx & 31;
      ((unsigned int*)&attn_s[i][0])[e2] =
          ((const unsigned int*)&attn_buf[(((size_t)bh*N_ + n)*C_ + i)*C_])[e2];
    }
    if (tid < C_) {
      size_t g = (size_t)bh*T_ + t0 + tid;
      float dv = dec_buf[g];
      dec_s[tid] = dv; edec[tid] = expf(dv); gate_s[tid] = gate_buf[g];
    }
    if (tid >= 64 && tid < 129) {
      int i = tid - 64;
      int tg = t0 - 1 + i;
      inn[i] = (tg >= 0) ? innorm_buf[(size_t)bh*T_ + tg] : 0.f;
    }
    __syncthreads();
    if (tid < C_) dw[tid] = expf(dec_s[C_-1] - dec_s[tid]);
    // --- v_new = v' - wkcd @ S ---
    {
      float4 a = *(const float4*)&v_io[((size_t)b*T_ + t0 + ib)*D_ + h*HD_ + e0b + cb4];
      const ushort_t* wr = &wkcd_s[ib*132];
      for (int k = 0; k < HD_; k += 4) {
        unsigned int u0 = *(const unsigned int*)&wr[k];
        unsigned int u1 = *(const unsigned int*)&wr[k+2];
        float w0 = bfu(u0 & 0xFFFFu), w1 = bfu(u0 >> 16);
        float w2 = bfu(u1 & 0xFFFFu), w3 = bfu(u1 >> 16);
        fma4(a, -w0, *(const float4*)&S[k  ][cb4]);
        fma4(a, -w1, *(const float4*)&S[k+1][cb4]);
        fma4(a, -w2, *(const float4*)&S[k+2][cb4]);
        fma4(a, -w3, *(const float4*)&S[k+3][cb4]);
      }
      *(float4*)&Vn[ib][cb4] = a;
    }
    __syncthreads();
    // --- load keys (fp32) over wkcd region ---
    for (int idx = tid; idx < 65*32; idx += 256) {
      int i = idx >> 5, e4 = (idx & 31) * 4;
      int tg = t0 - 1 + i;
      float4 v = {0.f,0.f,0.f,0.f};
      if (tg >= 0) {
        v = *(const float4*)&x[((size_t)b*T_ + tg)*D_ + h*HD_ + e4];
        float s = inn[i];
        v.x*=s; v.y*=s; v.z*=s; v.w*=s;
      }
      *(float4*)&PoolF[i*132 + e4] = v;
    }
    __syncthreads();
    // --- o = (rk@S)*e^dec + attn@v_new; store gated, in place ---
    {
      float4 o = {0.f,0.f,0.f,0.f};
      const float* rr = &PoolF[(ib+1)*132];
      for (int k = 0; k < HD_; k += 4) {
        float4 r4 = *(const float4*)&rr[k];
        fma4(o, r4.x, *(const float4*)&S[k  ][cb4]);
        fma4(o, r4.y, *(const float4*)&S[k+1][cb4]);
        fma4(o, r4.z, *(const float4*)&S[k+2][cb4]);
        fma4(o, r4.w, *(const float4*)&S[k+3][cb4]);
      }
      float ed = edec[ib];
      o.x*=ed; o.y*=ed; o.z*=ed; o.w*=ed;
      const int jend = (ib + 4) & ~3;
      for (int j = 0; j < jend; j += 4) {
        unsigned int u0 = *(const unsigned int*)&attn_s[ib][j];
        unsigned int u1 = *(const unsigned int*)&attn_s[ib][j+2];
        fma4(o, bfu(u0 & 0xFFFFu), *(const float4*)&Vn[j  ][cb4]);
        fma4(o, bfu(u0 >> 16),     *(const float4*)&Vn[j+1][cb4]);
        fma4(o, bfu(u1 & 0xFFFFu), *(const float4*)&Vn[j+2][cb4]);
        fma4(o, bfu(u1 >> 16),     *(const float4*)&Vn[j+3][cb4]);
      }
      float g = gate_s[ib];
      o.x*=g; o.y*=g; o.z*=g; o.w*=g;
      *(float4*)&v_io[((size_t)b*T_ + t0 + ib)*D_ + h*HD_ + e0b + cb4] = o;
    }
    __syncthreads();
    // --- S = S*e^dec[last] + (wk*dw)^T @ v_new ---
    {
      float el = edec[C_-1];
      float4 s0 = *(const float4*)&S[kr][cb8];
      float4 s1 = *(const float4*)&S[kr][cb8+4];
      s0.x*=el; s0.y*=el; s0.z*=el; s0.w*=el;
      s1.x*=el; s1.y*=el; s1.z*=el; s1.w*=el;
      for (int i = 0; i < C_; i++) {
        float w = PoolF[i*132 + kr] * dw[i];
        fma4(s0, w, *(const float4*)&Vn[i][cb8]);
        fma4(s1, w, *(const float4*)&Vn[i][cb8+4]);
      }
      *(float4*)&S[kr][cb8]   = s0;
      *(float4*)&S[kr][cb8+4] = s1;
    }
  }
}

// ---------------------------------------------------------------------------
extern "C" void kernel_launch(void* const* d_in, const int* in_sizes, int n_in,
                              void* d_out, int out_size, void* d_ws, size_t ws_size,
                              hipStream_t stream) {
  const float* x       = (const float*)d_in[0];
  const float* W_write = (const float*)d_in[1];
  const float* W_gate  = (const float*)d_in[2];
  const float* W_out   = (const float*)d_in[3];
  const float* W_beta  = (const float*)d_in[4];
  const float* W_alpha = (const float*)d_in[5];
  const float* dt_bias = (const float*)d_in[6];
  const float* A_log   = (const float*)d_in[7];
  float* out = (float*)d_out;

  const size_t SZ_BIG   = (size_t)BT_ * D_;                 // 33.5M elems
  const size_t SZ_ATTN  = (size_t)BH_ * N_ * C_ * C_;       // 16.8M elems
  const size_t SZ_SMALL = (size_t)BH_ * T_;                 // 262K elems

  float*    vraw = (float*)d_ws;                            // fp32, in-place v -> v' -> gated o
  ushort_t* wkcd = (ushort_t*)(vraw + SZ_BIG);              // bf16
  ushort_t* attn = wkcd + SZ_BIG;                           // bf16
  float*    decb = (float*)(attn + SZ_ATTN);
  float*    gateb  = decb + SZ_SMALL;
  float*    betab  = gateb + SZ_SMALL;
  float*    decayb = betab + SZ_SMALL;
  float*    innorm = decayb + SZ_SMALL;
  // total: 134.2 + 67.1 + 33.6 + 5*1.05 MB = ~240 MB

  k1_proj<<<BT_, 256, 0, stream>>>(x, W_gate, W_beta, W_alpha, dt_bias, A_log,
                                   gateb, betab, decayb, innorm);
  k_gemm<<<dim3(D_/128, BT_/128), 256, 0, stream>>>(x, W_write, nullptr, vraw,
                                                    BT_, D_, D_);
  k3_chunk<<<BH_*N_, 256, 0, stream>>>(x, vraw, betab, decayb, innorm,
                                       wkcd, attn, decb);
  k4_scan<<<BH_*8, 256, 0, stream>>>(x, vraw, wkcd, attn, decb, gateb, innorm);
  k_gemm<<<dim3(D_/128, BT_/128), 256, 0, stream>>>(vraw, W_out, x, out,
                                                    BT_, D_, D_);
}